// Round 14
// baseline (27.135 us; speedup 1.0000x reference)
//
#include <hip/hip_runtime.h>
#include <math.h>

#define B_SZ 4
#define C_IN 64
#define HW_ 576
#define PPLANE 728                    // 26*28 padded plane of h2 (channel pair)
#define XH_N   (B_SZ * 32 * PPLANE)   // 93184

typedef _Float16 h2 __attribute__((ext_vector_type(2)));
typedef _Float16 h8 __attribute__((ext_vector_type(8)));

static __device__ __forceinline__ float dot2(h2 a, h2 b, float c) {
#if __has_builtin(__builtin_amdgcn_fdot2)
  return __builtin_amdgcn_fdot2(a, b, c, false);
#else
  return c + (float)a.x * (float)b.x + (float)a.y * (float)b.y;
#endif
}

static __device__ __forceinline__ float frcp(float d) {
#if __has_builtin(__builtin_amdgcn_rcpf)
  return __builtin_amdgcn_rcpf(d);
#else
  return 1.0f / d;
#endif
}

// ---------------- K1: BN stats (redundant per block) + pack x to f16 -------
__global__ __launch_bounds__(256)
void stats_pack_kernel(const float* __restrict__ x, const float* __restrict__ gamma,
                       const float* __restrict__ beta, h2* __restrict__ xh) {
  const int bid = blockIdx.x, tid = threadIdx.x;
  const int icp = bid & 31, b = bid >> 5;
  __shared__ float rs[4], rss[4], ab[4];
  const int c = icp * 2 + (tid >> 7);
  float s = 0.f, ss = 0.f;
  for (int i = (tid & 127); i < B_SZ * HW_; i += 128) {
    int b2 = i / HW_, px = i - b2 * HW_;
    float v = x[(b2 * C_IN + c) * HW_ + px];
    s += v; ss = fmaf(v, v, ss);
  }
#pragma unroll
  for (int off = 32; off > 0; off >>= 1) {
    s += __shfl_down(s, off); ss += __shfl_down(ss, off);
  }
  if ((tid & 63) == 0) { rs[tid >> 6] = s; rss[tid >> 6] = ss; }
  __syncthreads();
  if (tid < 2) {
    float S = rs[tid * 2] + rs[tid * 2 + 1], SS = rss[tid * 2] + rss[tid * 2 + 1];
    const float inv_n = 1.f / (B_SZ * HW_);
    float mean = S * inv_n;
    float var  = SS * inv_n - mean * mean;
    float a = rsqrtf(var + 1e-5f) * gamma[icp * 2 + tid];
    ab[tid * 2] = a;
    ab[tid * 2 + 1] = fmaf(-mean, a, beta[icp * 2 + tid]);
  }
  __syncthreads();
  const float a0 = ab[0], b0 = ab[1], a1 = ab[2], b1 = ab[3];
  h2* plane = xh + (size_t)(b * 32 + icp) * PPLANE;
  const float* src0 = x + (size_t)(b * C_IN + icp * 2) * HW_;
  for (int e = tid; e < PPLANE; e += 256) {
    int rrow = e / 28, ecol = e - rrow * 28;
    int yy = rrow - 1, xx = ecol - 1;
    float f0 = 0.f, f1 = 0.f;
    if ((unsigned)yy < 24u && (unsigned)xx < 24u) {
      f0 = fmaf(src0[yy * 24 + xx],       a0, b0);
      f1 = fmaf(src0[HW_ + yy * 24 + xx], a1, b1);
    }
    h2 v; v.x = (_Float16)f0; v.y = (_Float16)f1;
    plane[e] = v;
  }
}

// ---------------- K2: fused qkv conv + barycentric rank-1 attention --------
// 1024 thr = 7 K-subs x 144 pixel-quads (+16 idle). icp per sub:
// {5,5,5,5,4,4,4}; the 5/4 branch boundary (tid 576) is wave-aligned.
// i=0 data loads peeled above the weight-staging barrier (prefetch).
__global__ __launch_bounds__(1024)
void qkv_attn_kernel(const h2* __restrict__ xh, const float* __restrict__ wq,
                     h2* __restrict__ outv) {
  const int bid = blockIdx.x, tid = threadIdx.x;
  const int b = bid >> 6, c = bid & 63;
  const int sub = tid / 144;
  const int r = tid - sub * 144;
  const int y = r / 6, x0 = (r % 6) * 4;
  const bool act = sub < 7;

  __shared__ __align__(16) char smem[52656];
  h2*    Wl  = (h2*)smem;                 // [32 icp][32 h2] (27 used) 4096B
  float* cb  = (float*)(smem + 4096);     // [6][3][144][4] f32, 41472B
  float* red2 = (float*)(smem + 4096);    // [144][20] overlays cb post-combine
  float2* kvs = (float2*)(smem + 45568);  // 576 float2
  float* qs  = (float*)(smem + 50176);    // 576 f32
  float* red = (float*)(smem + 52480);    // 20
  float* FGf = (float*)(smem + 52560);    // 18

  const int icp0 = (sub < 4) ? sub * 5 : 20 + (sub - 4) * 4;
  const int myN  = (sub < 4) ? 5 : 4;
  const h2* dbase = xh + ((size_t)(b * 32 + (act ? icp0 : 0)) * PPLANE + y * 28 + x0);

  // prologue: issue i=0 data loads before the barrier
  h8 pre[6];
  pre[0] = *(const h8*)(dbase);      pre[1] = *(const h8*)(dbase + 4);
  pre[2] = *(const h8*)(dbase + 28); pre[3] = *(const h8*)(dbase + 32);
  pre[4] = *(const h8*)(dbase + 56); pre[5] = *(const h8*)(dbase + 60);

  // pack this block's weights f32 -> f16 LDS (oc = {c, 64+c, 128+c})
  if (tid < 864) {
    int icp = tid / 27, rem = tid - icp * 27;
    int o = rem / 9, t = rem - o * 9;
    int oc = c + 64 * o;
    h2 v;
    v.x = (_Float16)wq[(oc * C_IN + 2 * icp) * 9 + t];
    v.y = (_Float16)wq[(oc * C_IN + 2 * icp + 1) * 9 + t];
    Wl[icp * 32 + rem] = v;
  }
  __syncthreads();

  float acc[3][4] = {{0.f,0.f,0.f,0.f},{0.f,0.f,0.f,0.f},{0.f,0.f,0.f,0.f}};
  if (act) {
#pragma unroll
    for (int i = 0; i < 5; ++i) {
      if (i < myN) {
        union { h8 v8[2]; h2 v2[8]; } R0, R1, R2;
        if (i == 0) {
          R0.v8[0] = pre[0]; R0.v8[1] = pre[1];
          R1.v8[0] = pre[2]; R1.v8[1] = pre[3];
          R2.v8[0] = pre[4]; R2.v8[1] = pre[5];
        } else {
          const h2* dp = dbase + i * PPLANE;
          R0.v8[0] = *(const h8*)(dp);      R0.v8[1] = *(const h8*)(dp + 4);
          R1.v8[0] = *(const h8*)(dp + 28); R1.v8[1] = *(const h8*)(dp + 32);
          R2.v8[0] = *(const h8*)(dp + 56); R2.v8[1] = *(const h8*)(dp + 60);
        }
        const h2* wrow = Wl + (icp0 + i) * 32;
        union { h8 v8[7]; h2 v2[28]; } W;      // 56 halves both ways
#pragma unroll
        for (int j8 = 0; j8 < 7; ++j8) W.v8[j8] = *(const h8*)(wrow + j8 * 4);
#pragma unroll
        for (int o = 0; o < 3; ++o) {
#pragma unroll
          for (int p = 0; p < 4; ++p) {
            float a = acc[o][p];
            a = dot2(R0.v2[p + 0], W.v2[o * 9 + 0], a);
            a = dot2(R0.v2[p + 1], W.v2[o * 9 + 1], a);
            a = dot2(R0.v2[p + 2], W.v2[o * 9 + 2], a);
            a = dot2(R1.v2[p + 0], W.v2[o * 9 + 3], a);
            a = dot2(R1.v2[p + 1], W.v2[o * 9 + 4], a);
            a = dot2(R1.v2[p + 2], W.v2[o * 9 + 5], a);
            a = dot2(R2.v2[p + 0], W.v2[o * 9 + 6], a);
            a = dot2(R2.v2[p + 1], W.v2[o * 9 + 7], a);
            a = dot2(R2.v2[p + 2], W.v2[o * 9 + 8], a);
            acc[o][p] = a;
          }
        }
      }
    }
  }
  __syncthreads();
  if (act && sub != 0) {
    const int base = (sub - 1) * 3 * 576;
#pragma unroll
    for (int o = 0; o < 3; ++o)
#pragma unroll
      for (int p = 0; p < 4; ++p)
        cb[base + o * 576 + r * 4 + p] = acc[o][p];
  }
  __syncthreads();
  const float scale_l2e = 0.125f * 1.44269504088896341f;  // 1/sqrt(64)*log2(e)
  if (sub == 0) {
#pragma unroll
    for (int p = 0; p < 4; ++p) {
      float qv = acc[0][p], kv = acc[1][p], vv = acc[2][p];
#pragma unroll
      for (int s6 = 0; s6 < 6; ++s6) {
        qv += cb[s6 * 1728 + 0 * 576 + r * 4 + p];
        kv += cb[s6 * 1728 + 1 * 576 + r * 4 + p];
        vv += cb[s6 * 1728 + 2 * 576 + r * 4 + p];
      }
      qs[4 * r + p] = qv * scale_l2e;        // pixel = 4r + p
      kvs[4 * r + p] = make_float2(kv, vv);
    }
  }
  __syncthreads();

  // ---- barycentric rank-1 attention (pixel tid, tid<576) ----
  const bool apx = tid < HW_;
  const float s = apx ? qs[tid] : 0.f;
  float smax = apx ? s : -1e30f, smin = apx ? s : 1e30f;
#pragma unroll
  for (int off = 32; off > 0; off >>= 1) {
    smax = fmaxf(smax, __shfl_down(smax, off));
    smin = fminf(smin, __shfl_down(smin, off));
  }
  const int wid = tid >> 6;
  if ((tid & 63) == 0 && apx) { red[wid] = smax; red[10 + wid] = smin; }
  __syncthreads();
  smax = red[0]; smin = red[10];
#pragma unroll
  for (int w = 1; w < 9; ++w) {
    smax = fmaxf(smax, red[w]); smin = fminf(smin, red[10 + w]);
  }
  const float cc = 0.5f * (smax + smin);
  const float rr = fmaxf(0.5f * (smax - smin), 1e-6f);
  const float COS[9] = { 0.98480775f,  0.86602540f,  0.64278761f,  0.34202014f, 0.f,
                        -0.34202014f, -0.64278761f, -0.86602540f, -0.98480775f };
  const float WJ[9]  = { 0.17364818f, -0.5f,  0.76604444f, -0.93969262f, 1.f,
                        -0.93969262f, 0.76604444f, -0.5f, 0.17364818f };
  float xj[9];
#pragma unroll
  for (int j = 0; j < 9; ++j) xj[j] = fmaf(rr, COS[j], cc);

  float fj[9], gj[9];
  {
    const float kk = apx ? kvs[tid].x : 0.f;
    const float vv = apx ? kvs[tid].y : 0.f;
#pragma unroll
    for (int j = 0; j < 9; ++j) {
      float E = apx ? __builtin_amdgcn_exp2f(xj[j] * kk) : 0.f;
      gj[j] = E; fj[j] = E * vv;
    }
  }
#pragma unroll
  for (int j = 0; j < 9; ++j) {
    fj[j] += __shfl_xor(fj[j], 1); gj[j] += __shfl_xor(gj[j], 1);
    fj[j] += __shfl_xor(fj[j], 2); gj[j] += __shfl_xor(gj[j], 2);
  }
  if ((tid & 3) == 0 && apx) {
    const int row = tid >> 2;       // 0..143
#pragma unroll
    for (int j = 0; j < 9; ++j) {
      red2[row * 20 + j] = fj[j];
      red2[row * 20 + 9 + j] = gj[j];
    }
  }
  __syncthreads();
  if (tid < 144) {
    const int j = tid >> 3, chunk = tid & 7;   // j in 0..17
    float sum = 0.f;
#pragma unroll
    for (int i = 0; i < 18; ++i) sum += red2[(chunk + 8 * i) * 20 + j];
    sum += __shfl_xor(sum, 1);
    sum += __shfl_xor(sum, 2);
    sum += __shfl_xor(sum, 4);
    if (chunk == 0) FGf[j] = sum;
  }
  __syncthreads();

  if (apx) {
    float num = 0.f, den = 0.f;
#pragma unroll
    for (int j = 0; j < 9; ++j) {
      float d = s - xj[j];
      d = copysignf(fmaxf(fabsf(d), 1e-7f), d);
      float mu = WJ[j] * frcp(d);
      num = fmaf(mu, FGf[j], num);
      den = fmaf(mu, FGf[9 + j], den);
    }
    float outval = num / den;

    const int icp = c >> 1, hc = c & 1;
    _Float16* plane = reinterpret_cast<_Float16*>(outv + ((size_t)(b * 32) + icp) * PPLANE);
    const int yy = tid / 24, xx = tid - yy * 24;
    plane[((yy + 1) * 28 + (xx + 1)) * 2 + hc] = (_Float16)outval;
    if (tid < 100) {  // zero halo (cols 26,27 never used by dot2s)
      int rrow, e;
      if (tid < 26)      { rrow = 0;            e = tid; }
      else if (tid < 52) { rrow = 25;           e = tid - 26; }
      else if (tid < 76) { rrow = tid - 52 + 1; e = 0; }
      else               { rrow = tid - 76 + 1; e = 25; }
      plane[(rrow * 28 + e) * 2 + hc] = (_Float16)0.f;
    }
  }
}

// ---------------- K3: out conv (OCG=1) + residual + final store ------------
__global__ __launch_bounds__(1024)
void conv_out_kernel(const h2* __restrict__ outv, const float* __restrict__ wo,
                     const float* __restrict__ x, float* __restrict__ out) {
  const int bid = blockIdx.x, tid = threadIdx.x;
  const int b = bid >> 6, oc = bid & 63;
  const int sub = tid / 144;
  const int r = tid - sub * 144;
  const int y = r / 6, x0 = (r % 6) * 4;
  const bool act = sub < 7;

  __shared__ __align__(16) char smem[15872];
  h2*    Wl = (h2*)smem;               // [32 icp][16 h2] (9 used) 2048B
  float* cb = (float*)(smem + 2048);   // [6][144][4] f32, 13824B

  const int icp0 = (sub < 4) ? sub * 5 : 20 + (sub - 4) * 4;
  const int myN  = (sub < 4) ? 5 : 4;
  const h2* dbase = outv + ((size_t)(b * 32 + (act ? icp0 : 0)) * PPLANE + y * 28 + x0);

  h8 pre[6];
  pre[0] = *(const h8*)(dbase);      pre[1] = *(const h8*)(dbase + 4);
  pre[2] = *(const h8*)(dbase + 28); pre[3] = *(const h8*)(dbase + 32);
  pre[4] = *(const h8*)(dbase + 56); pre[5] = *(const h8*)(dbase + 60);

  if (tid < 288) {
    int icp = tid / 9, t = tid - icp * 9;
    h2 v;  // scale 4096: dodge f16 subnormals (w_out ~ 7e-5)
    v.x = (_Float16)(wo[(oc * C_IN + 2 * icp) * 9 + t] * 4096.f);
    v.y = (_Float16)(wo[(oc * C_IN + 2 * icp + 1) * 9 + t] * 4096.f);
    Wl[icp * 16 + t] = v;
  }
  __syncthreads();

  float acc[4] = {0.f, 0.f, 0.f, 0.f};
  if (act) {
#pragma unroll
    for (int i = 0; i < 5; ++i) {
      if (i < myN) {
        union { h8 v8[2]; h2 v2[8]; } R0, R1, R2;
        if (i == 0) {
          R0.v8[0] = pre[0]; R0.v8[1] = pre[1];
          R1.v8[0] = pre[2]; R1.v8[1] = pre[3];
          R2.v8[0] = pre[4]; R2.v8[1] = pre[5];
        } else {
          const h2* dp = dbase + i * PPLANE;
          R0.v8[0] = *(const h8*)(dp);      R0.v8[1] = *(const h8*)(dp + 4);
          R1.v8[0] = *(const h8*)(dp + 28); R1.v8[1] = *(const h8*)(dp + 32);
          R2.v8[0] = *(const h8*)(dp + 56); R2.v8[1] = *(const h8*)(dp + 60);
        }
        const h2* wrow = Wl + (icp0 + i) * 16;
        union { h8 v8[3]; h2 v2[12]; } W;    // 24 halves both ways
        W.v8[0] = *(const h8*)(wrow);
        W.v8[1] = *(const h8*)(wrow + 4);
        W.v8[2] = *(const h8*)(wrow + 8);
#pragma unroll
        for (int p = 0; p < 4; ++p) {
          float a = acc[p];
          a = dot2(R0.v2[p + 0], W.v2[0], a);
          a = dot2(R0.v2[p + 1], W.v2[1], a);
          a = dot2(R0.v2[p + 2], W.v2[2], a);
          a = dot2(R1.v2[p + 0], W.v2[3], a);
          a = dot2(R1.v2[p + 1], W.v2[4], a);
          a = dot2(R1.v2[p + 2], W.v2[5], a);
          a = dot2(R2.v2[p + 0], W.v2[6], a);
          a = dot2(R2.v2[p + 1], W.v2[7], a);
          a = dot2(R2.v2[p + 2], W.v2[8], a);
          acc[p] = a;
        }
      }
    }
  }
  __syncthreads();
  if (act && sub != 0) {
    const int base = ((sub - 1) * 144 + r) * 4;
#pragma unroll
    for (int p = 0; p < 4; ++p) cb[base + p] = acc[p];
  }
  __syncthreads();
  if (sub == 0) {
    size_t idx = ((size_t)(b * C_IN + oc) * HW_) + 4 * r;
    float4 xr = *reinterpret_cast<const float4*>(x + idx);
    const float inv = 1.f / 4096.f;
    float sum[4];
#pragma unroll
    for (int p = 0; p < 4; ++p) {
      float a = acc[p];
#pragma unroll
      for (int s6 = 0; s6 < 6; ++s6) a += cb[(s6 * 144 + r) * 4 + p];
      sum[p] = a;
    }
    float4 v;
    v.x = fmaf(sum[0], inv, xr.x);
    v.y = fmaf(sum[1], inv, xr.y);
    v.z = fmaf(sum[2], inv, xr.z);
    v.w = fmaf(sum[3], inv, xr.w);
    *reinterpret_cast<float4*>(out + idx) = v;
  }
}

// ---------------- launch ---------------------------------------------------
extern "C" void kernel_launch(void* const* d_in, const int* in_sizes, int n_in,
                              void* d_out, int out_size, void* d_ws, size_t ws_size,
                              hipStream_t stream) {
  const float* x     = (const float*)d_in[0];
  const float* gamma = (const float*)d_in[1];
  const float* beta  = (const float*)d_in[2];
  const float* w_qkv = (const float*)d_in[3];
  const float* w_out = (const float*)d_in[4];
  float* out = (float*)d_out;

  h2* xh   = (h2*)d_ws;
  h2* outv = xh + XH_N;

  stats_pack_kernel<<<128, 256, 0, stream>>>(x, gamma, beta, xh);
  qkv_attn_kernel<<<256, 1024, 0, stream>>>(xh, w_qkv, outv);
  conv_out_kernel<<<256, 1024, 0, stream>>>(outv, w_out, x, out);
}

// Round 15
// 25.635 us; speedup vs baseline: 1.0585x; 1.0585x over previous
//
#include <hip/hip_runtime.h>
#include <math.h>

#define B_SZ 4
#define C_IN 64
#define HW_ 576
#define PPLANE 728                    // 26*28 padded plane of h2 (channel pair)
#define XH_N   (B_SZ * 32 * PPLANE)   // 93184

typedef _Float16 h2 __attribute__((ext_vector_type(2)));
typedef _Float16 h8 __attribute__((ext_vector_type(8)));

static __device__ __forceinline__ float dot2(h2 a, h2 b, float c) {
#if __has_builtin(__builtin_amdgcn_fdot2)
  return __builtin_amdgcn_fdot2(a, b, c, false);
#else
  return c + (float)a.x * (float)b.x + (float)a.y * (float)b.y;
#endif
}

static __device__ __forceinline__ float frcp(float d) {
#if __has_builtin(__builtin_amdgcn_rcpf)
  return __builtin_amdgcn_rcpf(d);
#else
  return 1.0f / d;
#endif
}

// ---------------- K1: BN stats (redundant) + pack x to f16 -----------------
// 256 blocks: (half = bid>>7, b = (bid>>5)&3, icp = bid&31). Both halves
// compute full stats (float4 loads); pack splits rows 0..12 / 13..25.
__global__ __launch_bounds__(256)
void stats_pack_kernel(const float* __restrict__ x, const float* __restrict__ gamma,
                       const float* __restrict__ beta, h2* __restrict__ xh) {
  const int bid = blockIdx.x, tid = threadIdx.x;
  const int icp = bid & 31, b = (bid >> 5) & 3, half = bid >> 7;
  __shared__ float rs[4], rss[4], ab[4];
  const int ch = icp * 2 + (tid >> 7);       // waves 0,1 -> ch0; 2,3 -> ch1
  const int lane128 = tid & 127;
  float s = 0.f, ss = 0.f;
#pragma unroll
  for (int b2 = 0; b2 < B_SZ; ++b2) {
    const float4* src4 = (const float4*)(x + (size_t)(b2 * C_IN + ch) * HW_);
    for (int i = lane128; i < 144; i += 128) {   // 576 floats = 144 float4
      float4 v = src4[i];
      s += v.x + v.y + v.z + v.w;
      ss = fmaf(v.x, v.x, ss); ss = fmaf(v.y, v.y, ss);
      ss = fmaf(v.z, v.z, ss); ss = fmaf(v.w, v.w, ss);
    }
  }
#pragma unroll
  for (int off = 32; off > 0; off >>= 1) {
    s += __shfl_down(s, off); ss += __shfl_down(ss, off);
  }
  if ((tid & 63) == 0) { rs[tid >> 6] = s; rss[tid >> 6] = ss; }
  __syncthreads();
  if (tid < 2) {
    float S = rs[tid * 2] + rs[tid * 2 + 1], SS = rss[tid * 2] + rss[tid * 2 + 1];
    const float inv_n = 1.f / (B_SZ * HW_);
    float mean = S * inv_n;
    float var  = SS * inv_n - mean * mean;
    float a = rsqrtf(var + 1e-5f) * gamma[icp * 2 + tid];
    ab[tid * 2] = a;
    ab[tid * 2 + 1] = fmaf(-mean, a, beta[icp * 2 + tid]);
  }
  __syncthreads();
  const float a0 = ab[0], b0 = ab[1], a1 = ab[2], b1 = ab[3];
  h2* plane = xh + (size_t)(b * 32 + icp) * PPLANE;
  const float* src0 = x + (size_t)(b * C_IN + icp * 2) * HW_;
  const int e0 = half * 364;                  // rows 0..12 / 13..25
  for (int e = e0 + tid; e < e0 + 364; e += 256) {
    int rrow = e / 28, ecol = e - rrow * 28;
    int yy = rrow - 1, xx = ecol - 1;
    float f0 = 0.f, f1 = 0.f;
    if ((unsigned)yy < 24u && (unsigned)xx < 24u) {
      f0 = fmaf(src0[yy * 24 + xx],       a0, b0);
      f1 = fmaf(src0[HW_ + yy * 24 + xx], a1, b1);
    }
    h2 v; v.x = (_Float16)f0; v.y = (_Float16)f1;
    plane[e] = v;
  }
}

// ---------------- K2: fused qkv conv + barycentric rank-1 attention --------
// 576 thr = 4 K-quarters x 144 pixel-quads (conv), then pixel-per-thread
// attention. Node sums: wave w owns Chebyshev node w (9 waves = 9 nodes).
__global__ __launch_bounds__(576)
void qkv_attn_kernel(const h2* __restrict__ xh, const float* __restrict__ wq,
                     h2* __restrict__ outv) {
  const int bid = blockIdx.x, tid = threadIdx.x;
  const int b = bid >> 6, c = bid & 63;
  const int sub = tid / 144;
  const int r = tid - sub * 144;
  const int y = r / 6, x0 = (r % 6) * 4;

  __shared__ __align__(16) char smem[31904];
  h2*    Wl  = (h2*)smem;                 // [32 icp][32 h2] (27 used) 4096B
  float* cb  = (float*)(smem + 4096);     // [3 subs][3][144][4] f32, 20736B
  float2* kvs = (float2*)(smem + 24832);  // 576 float2
  float* qs  = (float*)(smem + 29440);    // 576 f32
  float* red = (float*)(smem + 31744);    // 20
  float* FGf = (float*)(smem + 31824);    // 18

  // pack this block's weights f32 -> f16 LDS (oc = {c, 64+c, 128+c})
  for (int j = tid; j < 864; j += 576) {
    int icp = j / 27, rem = j - icp * 27;
    int o = rem / 9, t = rem - o * 9;
    int oc = c + 64 * o;
    h2 v;
    v.x = (_Float16)wq[(oc * C_IN + 2 * icp) * 9 + t];
    v.y = (_Float16)wq[(oc * C_IN + 2 * icp + 1) * 9 + t];
    Wl[icp * 32 + rem] = v;
  }
  __syncthreads();

  float acc[3][4] = {{0.f,0.f,0.f,0.f},{0.f,0.f,0.f,0.f},{0.f,0.f,0.f,0.f}};
  const int icp0 = sub * 8;
  const h2* dbase = xh + ((size_t)(b * 32 + icp0) * PPLANE + y * 28 + x0);
#pragma unroll
  for (int i = 0; i < 8; ++i) {
    const h2* dp = dbase + i * PPLANE;
    union { h8 v8[2]; h2 v2[8]; } R0, R1, R2;
    R0.v8[0] = *(const h8*)(dp);      R0.v8[1] = *(const h8*)(dp + 4);
    R1.v8[0] = *(const h8*)(dp + 28); R1.v8[1] = *(const h8*)(dp + 32);
    R2.v8[0] = *(const h8*)(dp + 56); R2.v8[1] = *(const h8*)(dp + 60);
    const h2* wrow = Wl + (icp0 + i) * 32;
    union { h8 v8[7]; h2 v2[28]; } W;      // 56 halves both ways
#pragma unroll
    for (int j8 = 0; j8 < 7; ++j8) W.v8[j8] = *(const h8*)(wrow + j8 * 4);
#pragma unroll
    for (int o = 0; o < 3; ++o) {
#pragma unroll
      for (int p = 0; p < 4; ++p) {
        float a = acc[o][p];
        a = dot2(R0.v2[p + 0], W.v2[o * 9 + 0], a);
        a = dot2(R0.v2[p + 1], W.v2[o * 9 + 1], a);
        a = dot2(R0.v2[p + 2], W.v2[o * 9 + 2], a);
        a = dot2(R1.v2[p + 0], W.v2[o * 9 + 3], a);
        a = dot2(R1.v2[p + 1], W.v2[o * 9 + 4], a);
        a = dot2(R1.v2[p + 2], W.v2[o * 9 + 5], a);
        a = dot2(R2.v2[p + 0], W.v2[o * 9 + 6], a);
        a = dot2(R2.v2[p + 1], W.v2[o * 9 + 7], a);
        a = dot2(R2.v2[p + 2], W.v2[o * 9 + 8], a);
        acc[o][p] = a;
      }
    }
  }
  __syncthreads();
  if (sub != 0) {
    const int base = (sub - 1) * 3 * 576;
#pragma unroll
    for (int o = 0; o < 3; ++o)
#pragma unroll
      for (int p = 0; p < 4; ++p)
        cb[base + o * 576 + r * 4 + p] = acc[o][p];
  }
  __syncthreads();
  const float scale_l2e = 0.125f * 1.44269504088896341f;  // 1/sqrt(64)*log2(e)
  if (sub == 0) {
#pragma unroll
    for (int p = 0; p < 4; ++p) {
      float qv = acc[0][p] + cb[0 * 576 + r * 4 + p]
               + cb[3 * 576 + r * 4 + p] + cb[6 * 576 + r * 4 + p];
      float kv = acc[1][p] + cb[1 * 576 + r * 4 + p]
               + cb[4 * 576 + r * 4 + p] + cb[7 * 576 + r * 4 + p];
      float vv = acc[2][p] + cb[2 * 576 + r * 4 + p]
               + cb[5 * 576 + r * 4 + p] + cb[8 * 576 + r * 4 + p];
      qs[4 * r + p] = qv * scale_l2e;        // pixel = 4r + p
      kvs[4 * r + p] = make_float2(kv, vv);
    }
  }
  __syncthreads();

  // ---- phase A: block range of s ----
  const float s = qs[tid];
  float smax = s, smin = s;
#pragma unroll
  for (int off = 32; off > 0; off >>= 1) {
    smax = fmaxf(smax, __shfl_down(smax, off));
    smin = fminf(smin, __shfl_down(smin, off));
  }
  const int wid = tid >> 6;
  if ((tid & 63) == 0) { red[wid] = smax; red[10 + wid] = smin; }
  __syncthreads();
  smax = red[0]; smin = red[10];
#pragma unroll
  for (int w = 1; w < 9; ++w) {
    smax = fmaxf(smax, red[w]); smin = fminf(smin, red[10 + w]);
  }
  const float cc = 0.5f * (smax + smin);
  const float rr = fmaxf(0.5f * (smax - smin), 1e-6f);
  const float COS[9] = { 0.98480775f,  0.86602540f,  0.64278761f,  0.34202014f, 0.f,
                        -0.34202014f, -0.64278761f, -0.86602540f, -0.98480775f };
  const float WJ[9]  = { 0.17364818f, -0.5f,  0.76604444f, -0.93969262f, 1.f,
                        -0.93969262f, 0.76604444f, -0.5f, 0.17364818f };
  float xj[9];
#pragma unroll
  for (int j = 0; j < 9; ++j) xj[j] = fmaf(rr, COS[j], cc);

  // ---- phase B: wave w sums node w over all 576 pixels ----
  {
    float xjw = xj[0];
#pragma unroll
    for (int j = 1; j < 9; ++j) if (wid == j) xjw = xj[j];  // wave-uniform
    const int lane = tid & 63;
    float fsum = 0.f, gsum = 0.f;
#pragma unroll
    for (int i = 0; i < 9; ++i) {
      float2 kv = kvs[lane + 64 * i];
      float E = __builtin_amdgcn_exp2f(xjw * kv.x);
      gsum += E;
      fsum = fmaf(E, kv.y, fsum);
    }
#pragma unroll
    for (int off = 32; off > 0; off >>= 1) {
      fsum += __shfl_down(fsum, off);
      gsum += __shfl_down(gsum, off);
    }
    if ((tid & 63) == 0) { FGf[wid] = fsum; FGf[9 + wid] = gsum; }
  }
  __syncthreads();

  // ---- phase C: barycentric ratio per pixel ----
  float num = 0.f, den = 0.f;
#pragma unroll
  for (int j = 0; j < 9; ++j) {
    float d = s - xj[j];
    d = copysignf(fmaxf(fabsf(d), 1e-7f), d);
    float mu = WJ[j] * frcp(d);
    num = fmaf(mu, FGf[j], num);
    den = fmaf(mu, FGf[9 + j], den);
  }
  float outval = num / den;

  const int icp = c >> 1, hc = c & 1;
  _Float16* plane = reinterpret_cast<_Float16*>(outv + ((size_t)(b * 32) + icp) * PPLANE);
  const int yy = tid / 24, xx = tid - yy * 24;
  plane[((yy + 1) * 28 + (xx + 1)) * 2 + hc] = (_Float16)outval;
  if (tid < 100) {  // zero halo (cols 26,27 never used by dot2s)
    int rrow, e;
    if (tid < 26)      { rrow = 0;            e = tid; }
    else if (tid < 52) { rrow = 25;           e = tid - 26; }
    else if (tid < 76) { rrow = tid - 52 + 1; e = 0; }
    else               { rrow = tid - 76 + 1; e = 25; }
    plane[(rrow * 28 + e) * 2 + hc] = (_Float16)0.f;
  }
}

// ---------------- K3: out conv (OCG=1) + residual + final store ------------
__global__ __launch_bounds__(576)
void conv_out_kernel(const h2* __restrict__ outv, const float* __restrict__ wo,
                     const float* __restrict__ x, float* __restrict__ out) {
  const int bid = blockIdx.x, tid = threadIdx.x;
  const int b = bid >> 6, oc = bid & 63;
  const int sub = tid / 144;
  const int r = tid - sub * 144;
  const int y = r / 6, x0 = (r % 6) * 4;

  __shared__ __align__(16) char smem[8960];
  h2*    Wl = (h2*)smem;               // [32 icp][16 h2] (9 used) 2048B
  float* cb = (float*)(smem + 2048);   // [3][144][4] f32, 6912B

  for (int j = tid; j < 288; j += 576) {
    int icp = j / 9, t = j - icp * 9;
    h2 v;  // scale 4096: dodge f16 subnormals (w_out ~ 7e-5)
    v.x = (_Float16)(wo[(oc * C_IN + 2 * icp) * 9 + t] * 4096.f);
    v.y = (_Float16)(wo[(oc * C_IN + 2 * icp + 1) * 9 + t] * 4096.f);
    Wl[icp * 16 + t] = v;
  }
  __syncthreads();

  float acc[4] = {0.f, 0.f, 0.f, 0.f};
  const int icp0 = sub * 8;
  const h2* dbase = outv + ((size_t)(b * 32 + icp0) * PPLANE + y * 28 + x0);
#pragma unroll
  for (int i = 0; i < 8; ++i) {
    const h2* dp = dbase + i * PPLANE;
    union { h8 v8[2]; h2 v2[8]; } R0, R1, R2;
    R0.v8[0] = *(const h8*)(dp);      R0.v8[1] = *(const h8*)(dp + 4);
    R1.v8[0] = *(const h8*)(dp + 28); R1.v8[1] = *(const h8*)(dp + 32);
    R2.v8[0] = *(const h8*)(dp + 56); R2.v8[1] = *(const h8*)(dp + 60);
    const h2* wrow = Wl + (icp0 + i) * 16;
    union { h8 v8[3]; h2 v2[12]; } W;    // 24 halves both ways
    W.v8[0] = *(const h8*)(wrow);
    W.v8[1] = *(const h8*)(wrow + 4);
    W.v8[2] = *(const h8*)(wrow + 8);
#pragma unroll
    for (int p = 0; p < 4; ++p) {
      float a = acc[p];
      a = dot2(R0.v2[p + 0], W.v2[0], a);
      a = dot2(R0.v2[p + 1], W.v2[1], a);
      a = dot2(R0.v2[p + 2], W.v2[2], a);
      a = dot2(R1.v2[p + 0], W.v2[3], a);
      a = dot2(R1.v2[p + 1], W.v2[4], a);
      a = dot2(R1.v2[p + 2], W.v2[5], a);
      a = dot2(R2.v2[p + 0], W.v2[6], a);
      a = dot2(R2.v2[p + 1], W.v2[7], a);
      a = dot2(R2.v2[p + 2], W.v2[8], a);
      acc[p] = a;
    }
  }
  __syncthreads();
  if (sub != 0) {
    const int base = ((sub - 1) * 144 + r) * 4;
#pragma unroll
    for (int p = 0; p < 4; ++p) cb[base + p] = acc[p];
  }
  __syncthreads();
  if (sub == 0) {
    size_t idx = ((size_t)(b * C_IN + oc) * HW_) + 4 * r;
    float4 xr = *reinterpret_cast<const float4*>(x + idx);
    const float inv = 1.f / 4096.f;
    float4 v;
    v.x = fmaf(acc[0] + cb[(0 * 144 + r) * 4 + 0] + cb[(1 * 144 + r) * 4 + 0] + cb[(2 * 144 + r) * 4 + 0], inv, xr.x);
    v.y = fmaf(acc[1] + cb[(0 * 144 + r) * 4 + 1] + cb[(1 * 144 + r) * 4 + 1] + cb[(2 * 144 + r) * 4 + 1], inv, xr.y);
    v.z = fmaf(acc[2] + cb[(0 * 144 + r) * 4 + 2] + cb[(1 * 144 + r) * 4 + 2] + cb[(2 * 144 + r) * 4 + 2], inv, xr.z);
    v.w = fmaf(acc[3] + cb[(0 * 144 + r) * 4 + 3] + cb[(1 * 144 + r) * 4 + 3] + cb[(2 * 144 + r) * 4 + 3], inv, xr.w);
    *reinterpret_cast<float4*>(out + idx) = v;
  }
}

// ---------------- launch ---------------------------------------------------
extern "C" void kernel_launch(void* const* d_in, const int* in_sizes, int n_in,
                              void* d_out, int out_size, void* d_ws, size_t ws_size,
                              hipStream_t stream) {
  const float* x     = (const float*)d_in[0];
  const float* gamma = (const float*)d_in[1];
  const float* beta  = (const float*)d_in[2];
  const float* w_qkv = (const float*)d_in[3];
  const float* w_out = (const float*)d_in[4];
  float* out = (float*)d_out;

  h2* xh   = (h2*)d_ws;
  h2* outv = xh + XH_N;

  stats_pack_kernel<<<256, 256, 0, stream>>>(x, gamma, beta, xh);
  qkv_attn_kernel<<<256, 576, 0, stream>>>(xh, w_qkv, outv);
  conv_out_kernel<<<256, 576, 0, stream>>>(outv, w_out, x, out);
}